// Round 1
// 9588.701 us; speedup vs baseline: 1.2743x; 1.2743x over previous
//
#include <hip/hip_runtime.h>
#include <math.h>

#define BATCH 64
#define SEQ 512
#define DIM 1024
#define HID 1024
#define KBANDS 4
#define DT_C 0.05f
#define CNT_STRIDE 32   // one counter per 128B line to kill same-line contention

// ---------------- alpha: softmax tau mixer -> alpha[b] ----------------
__global__ void alpha_kernel(const float* __restrict__ complexity,
                             const float* __restrict__ tau_bands,
                             const float* __restrict__ mixer_w,
                             const float* __restrict__ mixer_b,
                             float* __restrict__ alpha) {
    int b = threadIdx.x;
    if (b < BATCH) {
        float c = complexity[b];
        float lg[KBANDS];
        float mx = -1e30f;
        #pragma unroll
        for (int k = 0; k < KBANDS; k++) {
            lg[k] = c * mixer_w[k] + mixer_b[k];
            mx = fmaxf(mx, lg[k]);
        }
        float se = 0.f, tau = 0.f;
        #pragma unroll
        for (int k = 0; k < KBANDS; k++) {
            float e = expf(lg[k] - mx);
            se += e;
            tau += tau_bands[k] * e;
        }
        tau /= se;
        alpha[b] = expf(-DT_C / tau);
    }
}

// ------------- xw = x @ W_in^T + bias, written into d_out's output region -------------
#define BM 64
#define BN 64
#define BK 16
__global__ __launch_bounds__(256) void in_gemm(const float* __restrict__ x,
                                               const float* __restrict__ Win,
                                               const float* __restrict__ bias,
                                               float* __restrict__ out) {
    __shared__ float As[BK][BM + 4];
    __shared__ float Bs[BK][BN + 4];
    int tid = threadIdx.x;
    int tx = tid & 15, ty = tid >> 4;
    int m0 = blockIdx.x * BM;
    int n0 = blockIdx.y * BN;
    float c[4][4] = {};
    int lmm = tid >> 2;
    int lkq = (tid & 3) * 4;
    for (int k0 = 0; k0 < 1024; k0 += BK) {
        float4 a4 = *(const float4*)(x + (size_t)(m0 + lmm) * 1024 + k0 + lkq);
        float4 b4 = *(const float4*)(Win + (size_t)(n0 + lmm) * 1024 + k0 + lkq);
        As[lkq + 0][lmm] = a4.x; As[lkq + 1][lmm] = a4.y;
        As[lkq + 2][lmm] = a4.z; As[lkq + 3][lmm] = a4.w;
        Bs[lkq + 0][lmm] = b4.x; Bs[lkq + 1][lmm] = b4.y;
        Bs[lkq + 2][lmm] = b4.z; Bs[lkq + 3][lmm] = b4.w;
        __syncthreads();
        #pragma unroll
        for (int kk = 0; kk < BK; kk++) {
            float a[4], bb[4];
            #pragma unroll
            for (int i = 0; i < 4; i++) a[i] = As[kk][ty * 4 + i];
            #pragma unroll
            for (int j = 0; j < 4; j++) bb[j] = Bs[kk][tx * 4 + j];
            #pragma unroll
            for (int i = 0; i < 4; i++)
                #pragma unroll
                for (int j = 0; j < 4; j++)
                    c[i][j] += a[i] * bb[j];
        }
        __syncthreads();
    }
    int n = n0 + tx * 4;
    float4 bias4 = *(const float4*)(bias + n);
    #pragma unroll
    for (int i = 0; i < 4; i++) {
        int m = m0 + ty * 4 + i;
        float4 st;
        st.x = c[i][0] + bias4.x;
        st.y = c[i][1] + bias4.y;
        st.z = c[i][2] + bias4.z;
        st.w = c[i][3] + bias4.w;
        *(float4*)(out + (size_t)m * 1024 + n) = st;
    }
}

// ------------- cooperative recurrence --------------------------------------
// 256 blocks = 4 b-slices x 64 j-slices. Block tile per step: 16b x 16j x 1024k.
// W_rec slice (16 rows x 4KB) LDS-resident for the whole sequence.
// h[t] lives in `out` itself (out[b][t][j]); per-(t,bs) counters (padded to a
// cache line each) order producers against consumers.
// Sync primitives this revision:
//   - poll = relaxed agent atomic LOAD (sc1 read of coherence point; no RMW,
//     no per-poll buffer_inv) + s_sleep(1); rare RMW fallback kick as insurance
//   - ONE acquire fence (buffer_inv) per step after flag observed
//   - producer: release-only fence (buffer_wbl2) + RELAXED increment
#define PITCH 1028   // floats per LDS row (1024 + pad, mult of 4 for b128)
#define RPITCH 260

__global__ __launch_bounds__(256) void recur_coop(const float* __restrict__ Wrec,
                                                  const float* __restrict__ alpha,
                                                  float* __restrict__ out,
                                                  int* __restrict__ cnt) {
    extern __shared__ float lds[];
    float* wsl = lds;                 // [16][PITCH] W_rec rows js*16..+15
    float* hs  = lds + 16 * PITCH;    // [16][PITCH] h[t-1] for b-slice
    float* red = lds + 32 * PITCH;    // [16][RPITCH] k-split partials

    int tid = threadIdx.x;
    int bs = blockIdx.x & 3;          // b-slice 0..3
    int js = blockIdx.x >> 2;         // j-slice 0..63
    int ks = tid >> 4;                // 0..15 k-split
    int tb = (tid >> 2) & 3;          // 0..3 (4 b rows)
    int tj = tid & 3;                 // 0..3 (4 j rows)
    int bb = tid >> 4;                // 0..15 (staging / reduce row)
    int l16 = tid & 15;

    // stage W slice once
    {
        const float* src = Wrec + (size_t)(js * 16 + bb) * HID;
        float* dst = wsl + bb * PITCH;
        #pragma unroll
        for (int c = 0; c < 16; c++) {
            int j4 = l16 * 4 + c * 64;
            *(float4*)&dst[j4] = *(const float4*)&src[j4];
        }
    }
    float a_reg = alpha[bs * 16 + bb];
    float om = 1.f - a_reg;
    __syncthreads();

    int jglob = js * 16 + l16;
    int bglob = bs * 16 + bb;
    float* outb = out + (size_t)bglob * SEQ * HID;

    for (int t = 0; t < SEQ; t++) {
        float sum = 0.f, hp = 0.f;
        if (t > 0) {
            if (tid == 0) {
                int* cp = cnt + (size_t)((t - 1) * 4 + bs) * CNT_STRIDE;
                int spins = 0;
                while (__hip_atomic_load(cp, __ATOMIC_RELAXED,
                                         __HIP_MEMORY_SCOPE_AGENT) < 64) {
                    __builtin_amdgcn_s_sleep(1);
                    if (++spins >= 4096) {   // insurance: coherent RMW re-check
                        spins = 0;
                        if (__hip_atomic_fetch_add(cp, 0, __ATOMIC_RELAXED,
                                __HIP_MEMORY_SCOPE_AGENT) >= 64) break;
                    }
                }
                // one L2 invalidate per step (covers stale shared lines), not per poll
                __builtin_amdgcn_fence(__ATOMIC_ACQUIRE, "agent");
            }
            __syncthreads();
            // stage h[t-1] for our 16 batches
            {
                const float* srcb = out + ((size_t)bglob * SEQ + (t - 1)) * HID;
                float* dst = hs + bb * PITCH;
                #pragma unroll
                for (int c = 0; c < 16; c++) {
                    int j4 = l16 * 4 + c * 64;
                    *(float4*)&dst[j4] = *(const float4*)&srcb[j4];
                }
            }
            __syncthreads();
            float cacc[4][4] = {};
            #pragma unroll 4
            for (int m = 0; m < 16; m++) {
                int k = ks * 4 + m * 64;
                float4 av[4], bv[4];
                #pragma unroll
                for (int i = 0; i < 4; i++)
                    av[i] = *(const float4*)&hs[(tb * 4 + i) * PITCH + k];
                #pragma unroll
                for (int i = 0; i < 4; i++)
                    bv[i] = *(const float4*)&wsl[(tj * 4 + i) * PITCH + k];
                #pragma unroll
                for (int i = 0; i < 4; i++)
                    #pragma unroll
                    for (int j = 0; j < 4; j++)
                        cacc[i][j] += av[i].x * bv[j].x + av[i].y * bv[j].y
                                    + av[i].z * bv[j].z + av[i].w * bv[j].w;
            }
            #pragma unroll
            for (int i = 0; i < 4; i++) {
                float4 st; st.x = cacc[i][0]; st.y = cacc[i][1];
                st.z = cacc[i][2]; st.w = cacc[i][3];
                *(float4*)&red[ks * RPITCH + (tb * 4 + i) * 16 + tj * 4] = st;
            }
            __syncthreads();
            #pragma unroll 4
            for (int k2 = 0; k2 < 16; k2++) sum += red[k2 * RPITCH + tid];
            hp = hs[bb * PITCH + jglob];
        }
        float pre = sum + outb[(size_t)t * HID + jglob];
        float hn = a_reg * hp + om * tanhf(pre);
        outb[(size_t)t * HID + jglob] = hn;
        if (t == SEQ - 1)
            out[(size_t)BATCH * SEQ * HID + (size_t)bglob * HID + jglob] = hn;
        __syncthreads();   // all tile writes drained to L2 (barrier waits vmcnt)
        if (tid == 0) {
            // release-only: write back dirty L2 (our tile) to coherence point,
            // then relaxed far-atomic increment of this step's padded counter
            __builtin_amdgcn_fence(__ATOMIC_RELEASE, "agent");
            __hip_atomic_fetch_add(cnt + (size_t)(t * 4 + bs) * CNT_STRIDE, 1,
                    __ATOMIC_RELAXED, __HIP_MEMORY_SCOPE_AGENT);
        }
    }
}

extern "C" void kernel_launch(void* const* d_in, const int* in_sizes, int n_in,
                              void* d_out, int out_size, void* d_ws, size_t ws_size,
                              hipStream_t stream) {
    const float* x          = (const float*)d_in[0];
    const float* complexity = (const float*)d_in[1];
    const float* Wrec       = (const float*)d_in[2];
    const float* Win        = (const float*)d_in[3];
    const float* bias       = (const float*)d_in[4];
    const float* tau_bands  = (const float*)d_in[5];
    const float* mixer_w    = (const float*)d_in[6];
    const float* mixer_b    = (const float*)d_in[7];
    float* out = (float*)d_out;

    float* alpha = (float*)d_ws;                 // 64 floats
    int*   cnt   = (int*)d_ws + 64;              // 512*4 padded counters (128B apart)

    hipMemsetAsync(cnt, 0, SEQ * 4 * CNT_STRIDE * sizeof(int), stream);
    alpha_kernel<<<1, 64, 0, stream>>>(complexity, tau_bands, mixer_w, mixer_b, alpha);
    in_gemm<<<dim3(32768 / BM, 1024 / BN), 256, 0, stream>>>(x, Win, bias, out);

    const int ldsBytes = (32 * PITCH + 16 * RPITCH) * (int)sizeof(float);  // 148224
    hipFuncSetAttribute((const void*)recur_coop,
                        hipFuncAttributeMaxDynamicSharedMemorySize, ldsBytes);
    void* args[] = { (void*)&Wrec, (void*)&alpha, (void*)&out, (void*)&cnt };
    hipLaunchCooperativeKernel((void*)recur_coop, dim3(256), dim3(256),
                               args, ldsBytes, stream);
}

// Round 2
// 4487.252 us; speedup vs baseline: 2.7230x; 2.1369x over previous
//
#include <hip/hip_runtime.h>
#include <math.h>

#define BATCH 64
#define SEQ 512
#define DIM 1024
#define HID 1024
#define KBANDS 4
#define DT_C 0.05f
#define CNT_STRIDE 32   // one counter per 128B line to kill same-line contention

// ---------------- alpha: softmax tau mixer -> alpha[b] ----------------
__global__ void alpha_kernel(const float* __restrict__ complexity,
                             const float* __restrict__ tau_bands,
                             const float* __restrict__ mixer_w,
                             const float* __restrict__ mixer_b,
                             float* __restrict__ alpha) {
    int b = threadIdx.x;
    if (b < BATCH) {
        float c = complexity[b];
        float lg[KBANDS];
        float mx = -1e30f;
        #pragma unroll
        for (int k = 0; k < KBANDS; k++) {
            lg[k] = c * mixer_w[k] + mixer_b[k];
            mx = fmaxf(mx, lg[k]);
        }
        float se = 0.f, tau = 0.f;
        #pragma unroll
        for (int k = 0; k < KBANDS; k++) {
            float e = expf(lg[k] - mx);
            se += e;
            tau += tau_bands[k] * e;
        }
        tau /= se;
        alpha[b] = expf(-DT_C / tau);
    }
}

// ------------- xw = x @ W_in^T + bias, written into d_out's output region -------------
#define BM 64
#define BN 64
#define BK 16
__global__ __launch_bounds__(256) void in_gemm(const float* __restrict__ x,
                                               const float* __restrict__ Win,
                                               const float* __restrict__ bias,
                                               float* __restrict__ out) {
    __shared__ float As[BK][BM + 4];
    __shared__ float Bs[BK][BN + 4];
    int tid = threadIdx.x;
    int tx = tid & 15, ty = tid >> 4;
    int m0 = blockIdx.x * BM;
    int n0 = blockIdx.y * BN;
    float c[4][4] = {};
    int lmm = tid >> 2;
    int lkq = (tid & 3) * 4;
    for (int k0 = 0; k0 < 1024; k0 += BK) {
        float4 a4 = *(const float4*)(x + (size_t)(m0 + lmm) * 1024 + k0 + lkq);
        float4 b4 = *(const float4*)(Win + (size_t)(n0 + lmm) * 1024 + k0 + lkq);
        As[lkq + 0][lmm] = a4.x; As[lkq + 1][lmm] = a4.y;
        As[lkq + 2][lmm] = a4.z; As[lkq + 3][lmm] = a4.w;
        Bs[lkq + 0][lmm] = b4.x; Bs[lkq + 1][lmm] = b4.y;
        Bs[lkq + 2][lmm] = b4.z; Bs[lkq + 3][lmm] = b4.w;
        __syncthreads();
        #pragma unroll
        for (int kk = 0; kk < BK; kk++) {
            float a[4], bb[4];
            #pragma unroll
            for (int i = 0; i < 4; i++) a[i] = As[kk][ty * 4 + i];
            #pragma unroll
            for (int j = 0; j < 4; j++) bb[j] = Bs[kk][tx * 4 + j];
            #pragma unroll
            for (int i = 0; i < 4; i++)
                #pragma unroll
                for (int j = 0; j < 4; j++)
                    c[i][j] += a[i] * bb[j];
        }
        __syncthreads();
    }
    int n = n0 + tx * 4;
    float4 bias4 = *(const float4*)(bias + n);
    #pragma unroll
    for (int i = 0; i < 4; i++) {
        int m = m0 + ty * 4 + i;
        float4 st;
        st.x = c[i][0] + bias4.x;
        st.y = c[i][1] + bias4.y;
        st.z = c[i][2] + bias4.z;
        st.w = c[i][3] + bias4.w;
        *(float4*)(out + (size_t)m * 1024 + n) = st;
    }
}

// ------------- cooperative recurrence --------------------------------------
// 256 blocks = 4 b-slices x 64 j-slices. Block tile per step: 16b x 16j x 1024k.
// W_rec slice (16 rows x 4KB) LDS-resident for the whole sequence.
// h[t] lives in `out` itself (out[b][t][j]).
// Sync this revision: NO bulk cache ops (no buffer_wbl2 release, no buffer_inv
// acquire). Device-scope fine-grained handoff instead:
//   producer: h stores via global_store_dword sc0 sc1 (write-through to the
//             coherence point) -> vmcnt(0) -> barrier -> RELAXED flag inc
//   consumer: relaxed poll of the flag; h[t-1] staged via
//             global_load_dwordx4 sc0 sc1 (device-scope, cannot hit stale
//             local L1/L2). xw load hoisted above the poll to overlap latency.
// Stale-copy safety: the only plain read of an h-carrying line is the xw read
// at step t, which precedes h[t] being written to that line and is never
// re-read plainly; every later read of that line is an sc1 staging read.
#define PITCH 1028   // floats per LDS row (1024 + pad, mult of 4 for b128)
#define RPITCH 260

__device__ __forceinline__ void store_f1_dev(float* p, float v) {
    asm volatile("global_store_dword %0, %1, off sc0 sc1"
                 :: "v"(p), "v"(v) : "memory");
}

__global__ __launch_bounds__(256) void recur_coop(const float* __restrict__ Wrec,
                                                  const float* __restrict__ alpha,
                                                  float* __restrict__ out,
                                                  int* __restrict__ cnt) {
    extern __shared__ float lds[];
    float* wsl = lds;                 // [16][PITCH] W_rec rows js*16..+15
    float* hs  = lds + 16 * PITCH;    // [16][PITCH] h[t-1] for b-slice
    float* red = lds + 32 * PITCH;    // [16][RPITCH] k-split partials

    int tid = threadIdx.x;
    int bs = blockIdx.x & 3;          // b-slice 0..3
    int js = blockIdx.x >> 2;         // j-slice 0..63
    int ks = tid >> 4;                // 0..15 k-split
    int tb = (tid >> 2) & 3;          // 0..3 (4 b rows)
    int tj = tid & 3;                 // 0..3 (4 j rows)
    int bb = tid >> 4;                // 0..15 (staging / reduce row)
    int l16 = tid & 15;

    // stage W slice once
    {
        const float* src = Wrec + (size_t)(js * 16 + bb) * HID;
        float* dst = wsl + bb * PITCH;
        #pragma unroll
        for (int c = 0; c < 16; c++) {
            int j4 = l16 * 4 + c * 64;
            *(float4*)&dst[j4] = *(const float4*)&src[j4];
        }
    }
    float a_reg = alpha[bs * 16 + bb];
    float om = 1.f - a_reg;
    __syncthreads();

    int jglob = js * 16 + l16;
    int bglob = bs * 16 + bb;
    float* outb = out + (size_t)bglob * SEQ * HID;

    for (int t = 0; t < SEQ; t++) {
        // xw is independent of h[t-1]; issue it before the flag wait
        float xw = outb[(size_t)t * HID + jglob];
        float sum = 0.f, hp = 0.f;
        if (t > 0) {
            if (tid == 0) {
                int* cp = cnt + (size_t)((t - 1) * 4 + bs) * CNT_STRIDE;
                int spins = 0;
                while (__hip_atomic_load(cp, __ATOMIC_RELAXED,
                                         __HIP_MEMORY_SCOPE_AGENT) < 64) {
                    __builtin_amdgcn_s_sleep(1);
                    if (++spins >= 4096) {   // insurance: coherent RMW re-check
                        spins = 0;
                        if (__hip_atomic_fetch_add(cp, 0, __ATOMIC_RELAXED,
                                __HIP_MEMORY_SCOPE_AGENT) >= 64) break;
                    }
                }
            }
            __syncthreads();
            // stage h[t-1] for our 16 batches via device-scope (sc1) loads
            {
                const float* srcb = out + ((size_t)bglob * SEQ + (t - 1)) * HID;
                const float* base = srcb + l16 * 4;
                float* dst = hs + bb * PITCH + l16 * 4;
                float4 v[16];
                #pragma unroll
                for (int c = 0; c < 16; c++) {
                    asm volatile("global_load_dwordx4 %0, %1, off offset:%2 sc0 sc1"
                                 : "=v"(v[c]) : "v"(base), "i"(c * 256) : "memory");
                }
                asm volatile("s_waitcnt vmcnt(0)" ::: "memory");
                #pragma unroll
                for (int c = 0; c < 16; c++)
                    *(float4*)&dst[c * 64] = v[c];
            }
            __syncthreads();
            float cacc[4][4] = {};
            #pragma unroll 4
            for (int m = 0; m < 16; m++) {
                int k = ks * 4 + m * 64;
                float4 av[4], bv[4];
                #pragma unroll
                for (int i = 0; i < 4; i++)
                    av[i] = *(const float4*)&hs[(tb * 4 + i) * PITCH + k];
                #pragma unroll
                for (int i = 0; i < 4; i++)
                    bv[i] = *(const float4*)&wsl[(tj * 4 + i) * PITCH + k];
                #pragma unroll
                for (int i = 0; i < 4; i++)
                    #pragma unroll
                    for (int j = 0; j < 4; j++)
                        cacc[i][j] += av[i].x * bv[j].x + av[i].y * bv[j].y
                                    + av[i].z * bv[j].z + av[i].w * bv[j].w;
            }
            #pragma unroll
            for (int i = 0; i < 4; i++) {
                float4 st; st.x = cacc[i][0]; st.y = cacc[i][1];
                st.z = cacc[i][2]; st.w = cacc[i][3];
                *(float4*)&red[ks * RPITCH + (tb * 4 + i) * 16 + tj * 4] = st;
            }
            __syncthreads();
            #pragma unroll 4
            for (int k2 = 0; k2 < 16; k2++) sum += red[k2 * RPITCH + tid];
            hp = hs[bb * PITCH + jglob];
        }
        float pre = sum + xw;
        float hn = a_reg * hp + om * tanhf(pre);
        // device-scope write-through: visible at the coherence point once
        // vmcnt retires; no bulk wbl2 needed
        store_f1_dev(&outb[(size_t)t * HID + jglob], hn);
        if (t == SEQ - 1)
            out[(size_t)BATCH * SEQ * HID + (size_t)bglob * HID + jglob] = hn;
        asm volatile("s_waitcnt vmcnt(0)" ::: "memory");  // drain asm stores
        __syncthreads();
        if (tid == 0) {
            __hip_atomic_fetch_add(cnt + (size_t)(t * 4 + bs) * CNT_STRIDE, 1,
                    __ATOMIC_RELAXED, __HIP_MEMORY_SCOPE_AGENT);
        }
    }
}

extern "C" void kernel_launch(void* const* d_in, const int* in_sizes, int n_in,
                              void* d_out, int out_size, void* d_ws, size_t ws_size,
                              hipStream_t stream) {
    const float* x          = (const float*)d_in[0];
    const float* complexity = (const float*)d_in[1];
    const float* Wrec       = (const float*)d_in[2];
    const float* Win        = (const float*)d_in[3];
    const float* bias       = (const float*)d_in[4];
    const float* tau_bands  = (const float*)d_in[5];
    const float* mixer_w    = (const float*)d_in[6];
    const float* mixer_b    = (const float*)d_in[7];
    float* out = (float*)d_out;

    float* alpha = (float*)d_ws;                 // 64 floats
    int*   cnt   = (int*)d_ws + 64;              // 512*4 padded counters (128B apart)

    hipMemsetAsync(cnt, 0, SEQ * 4 * CNT_STRIDE * sizeof(int), stream);
    alpha_kernel<<<1, 64, 0, stream>>>(complexity, tau_bands, mixer_w, mixer_b, alpha);
    in_gemm<<<dim3(32768 / BM, 1024 / BN), 256, 0, stream>>>(x, Win, bias, out);

    const int ldsBytes = (32 * PITCH + 16 * RPITCH) * (int)sizeof(float);  // 148224
    hipFuncSetAttribute((const void*)recur_coop,
                        hipFuncAttributeMaxDynamicSharedMemorySize, ldsBytes);
    void* args[] = { (void*)&Wrec, (void*)&alpha, (void*)&out, (void*)&cnt };
    hipLaunchCooperativeKernel((void*)recur_coop, dim3(256), dim3(256),
                               args, ldsBytes, stream);
}

// Round 5
// 2870.776 us; speedup vs baseline: 4.2563x; 1.5631x over previous
//
#include <hip/hip_runtime.h>
#include <math.h>

#define BATCH 64
#define SEQ 512
#define DIM 1024
#define HID 1024
#define KBANDS 4
#define DT_C 0.05f
#define CNT_STRIDE 32   // one counter per 128B line

// ---------------- alpha: softmax tau mixer -> alpha[b] ----------------
__global__ void alpha_kernel(const float* __restrict__ complexity,
                             const float* __restrict__ tau_bands,
                             const float* __restrict__ mixer_w,
                             const float* __restrict__ mixer_b,
                             float* __restrict__ alpha) {
    int b = threadIdx.x;
    if (b < BATCH) {
        float c = complexity[b];
        float lg[KBANDS];
        float mx = -1e30f;
        #pragma unroll
        for (int k = 0; k < KBANDS; k++) {
            lg[k] = c * mixer_w[k] + mixer_b[k];
            mx = fmaxf(mx, lg[k]);
        }
        float se = 0.f, tau = 0.f;
        #pragma unroll
        for (int k = 0; k < KBANDS; k++) {
            float e = expf(lg[k] - mx);
            se += e;
            tau += tau_bands[k] * e;
        }
        tau /= se;
        alpha[b] = expf(-DT_C / tau);
    }
}

// ------------- xw = x @ W_in^T + bias, written into d_out's output region -------------
#define BM 64
#define BN 64
#define BK 16
__global__ __launch_bounds__(256) void in_gemm(const float* __restrict__ x,
                                               const float* __restrict__ Win,
                                               const float* __restrict__ bias,
                                               float* __restrict__ out) {
    __shared__ float As[BK][BM + 4];
    __shared__ float Bs[BK][BN + 4];
    int tid = threadIdx.x;
    int tx = tid & 15, ty = tid >> 4;
    int m0 = blockIdx.x * BM;
    int n0 = blockIdx.y * BN;
    float c[4][4] = {};
    int lmm = tid >> 2;
    int lkq = (tid & 3) * 4;
    for (int k0 = 0; k0 < 1024; k0 += BK) {
        float4 a4 = *(const float4*)(x + (size_t)(m0 + lmm) * 1024 + k0 + lkq);
        float4 b4 = *(const float4*)(Win + (size_t)(n0 + lmm) * 1024 + k0 + lkq);
        As[lkq + 0][lmm] = a4.x; As[lkq + 1][lmm] = a4.y;
        As[lkq + 2][lmm] = a4.z; As[lkq + 3][lmm] = a4.w;
        Bs[lkq + 0][lmm] = b4.x; Bs[lkq + 1][lmm] = b4.y;
        Bs[lkq + 2][lmm] = b4.z; Bs[lkq + 3][lmm] = b4.w;
        __syncthreads();
        #pragma unroll
        for (int kk = 0; kk < BK; kk++) {
            float a[4], bb[4];
            #pragma unroll
            for (int i = 0; i < 4; i++) a[i] = As[kk][ty * 4 + i];
            #pragma unroll
            for (int j = 0; j < 4; j++) bb[j] = Bs[kk][tx * 4 + j];
            #pragma unroll
            for (int i = 0; i < 4; i++)
                #pragma unroll
                for (int j = 0; j < 4; j++)
                    c[i][j] += a[i] * bb[j];
        }
        __syncthreads();
    }
    int n = n0 + tx * 4;
    float4 bias4 = *(const float4*)(bias + n);
    #pragma unroll
    for (int i = 0; i < 4; i++) {
        int m = m0 + ty * 4 + i;
        float4 st;
        st.x = c[i][0] + bias4.x;
        st.y = c[i][1] + bias4.y;
        st.z = c[i][2] + bias4.z;
        st.w = c[i][3] + bias4.w;
        *(float4*)(out + (size_t)m * 1024 + n) = st;
    }
}

// ------------- cooperative recurrence (bf16x3 MFMA, R2 sync skeleton) -------
// 256 blocks = 4 b-slices x 64 j-slices; 4 waves/block. Wave w owns k-quarter
// [256w, 256w+256).
// h is exchanged as bf16 hi/lo PLANES in a 512KB workspace double buffer
// (hbuf[parity][plane][64][1024] ushort): producer thread splits its OWN h
// value once (~8 VALU) and sc1-stores 2 shorts; consumers sc1-load shorts
// straight into LDS planes -> bf16x8 fragments -> MFMA. No in-loop float
// conversion, no LDS swizzle (plain 2064B-pitch rows), no asm LDS.
// fp32 h also stored PLAIN to out (output only; no cross-block reads of out's
// h region remain -> plain is safe; kernel-end flushes dirty L2).
// pre = Ah*Wh + Al*Wh + Ah*Wl (lo*lo dropped, ~1e-5). W frags converted once
// into registers (wh/wl[8], 64 VGPRs; launch_bounds(256,1) prevents spill).
// Sync = R2 verbatim: per-(t,bs) padded counters; tid0 relaxed poll ->
// syncthreads; epilogue: stores -> vmcnt(0) -> syncthreads -> tid0 +1.

#define HPITCH 2064               // bytes per LDS plane row (1024*2 + 16 pad)
#define LDS_HI  0
#define LDS_LO  33024             // 16*HPITCH
#define LDS_RED 66048             // 4KB reduction buffer
#define LDS_TOTAL 70144
#define HB_PLANE 131072           // bytes per plane [64][1024] ushort
#define HB_PARITY 262144          // 2 planes

typedef short bf16x8 __attribute__((ext_vector_type(8)));
typedef float f32x4 __attribute__((ext_vector_type(4)));

__device__ __forceinline__ unsigned bf16rn(float x) {
    unsigned u = __float_as_uint(x);
    return (u + 0x7fffu + ((u >> 16) & 1u)) >> 16;
}

__device__ __forceinline__ void splitf(float f, unsigned short* hi, unsigned short* lo) {
    unsigned h = bf16rn(f);
    float r = f - __uint_as_float(h << 16);
    *hi = (unsigned short)h;
    *lo = (unsigned short)bf16rn(r);
}

__global__ __launch_bounds__(256, 1) void recur_coop(const float* __restrict__ Wrec,
                                                     const float* __restrict__ alpha,
                                                     float* __restrict__ out,
                                                     int* __restrict__ cnt,
                                                     unsigned short* __restrict__ hbuf) {
    extern __shared__ char lbase[];

    int tid  = threadIdx.x;
    int bs   = blockIdx.x & 3;        // b-slice 0..3
    int js   = blockIdx.x >> 2;       // j-slice 0..63
    int lane = tid & 63;
    int w    = tid >> 6;              // wave 0..3 = k-quarter owner
    int row  = lane & 15;             // frag row: batch (A) / j (B)
    int kq   = lane >> 4;             // k-subchunk within 32-wide MFMA window

    // ---- W fragments (B operand), converted ONCE into registers ----------
    bf16x8 wh[8], wl[8];
    {
        const float* wsrc = Wrec + (size_t)(js * 16 + row) * HID + w * 256 + kq * 8;
        #pragma unroll
        for (int ks = 0; ks < 8; ks++) {
            float4 f0 = *(const float4*)(wsrc + ks * 32);
            float4 f1 = *(const float4*)(wsrc + ks * 32 + 4);
            union { unsigned short u[8]; bf16x8 v; } H, L;
            splitf(f0.x, &H.u[0], &L.u[0]);
            splitf(f0.y, &H.u[1], &L.u[1]);
            splitf(f0.z, &H.u[2], &L.u[2]);
            splitf(f0.w, &H.u[3], &L.u[3]);
            splitf(f1.x, &H.u[4], &L.u[4]);
            splitf(f1.y, &H.u[5], &L.u[5]);
            splitf(f1.z, &H.u[6], &L.u[6]);
            splitf(f1.w, &H.u[7], &L.u[7]);
            wh[ks] = H.v;
            wl[ks] = L.v;
        }
    }

    // epilogue mapping: thread owns (batch bs*16 + eb, hidden j js*16 + ej)
    int eb = tid >> 4;
    int ej = tid & 15;
    int bglob = bs * 16 + eb;
    int jglob = js * 16 + ej;
    float a_reg = alpha[bglob];
    float om = 1.f - a_reg;
    float* xwp = out + (size_t)bglob * SEQ * HID + jglob;

    // staging mapping: srow = batch row 0..15, sl16 = k-chunk lane
    int srow = tid >> 4, sl16 = tid & 15;
    // per-lane global byte offset inside a plane: (bs*16+srow)*2048 + sl16*16
    const char* hb_lane = (const char*)hbuf + (size_t)(bs * 16 + srow) * 2048 + sl16 * 16;
    // producer store pointers (parity added per step)
    char* ph_base = (char*)hbuf + (size_t)bglob * 2048 + jglob * 2;

    float hp = 0.f;
    float* redp = (float*)(lbase + LDS_RED);
    const char* ah_base = lbase + LDS_HI + row * HPITCH + (w * 256 + kq * 8) * 2;
    const char* al_base = lbase + LDS_LO + row * HPITCH + (w * 256 + kq * 8) * 2;
    char* dh = lbase + LDS_HI + srow * HPITCH + sl16 * 16;
    char* dl = lbase + LDS_LO + srow * HPITCH + sl16 * 16;

    for (int t = 0; t < SEQ; t++) {
        float xw = *xwp;              // independent of h[t-1]; issue early
        float sum = 0.f;
        if (t > 0) {
            if (tid == 0) {
                int* cp = cnt + (size_t)((t - 1) * 4 + bs) * CNT_STRIDE;
                int spins = 0;
                while (__hip_atomic_load(cp, __ATOMIC_RELAXED,
                                         __HIP_MEMORY_SCOPE_AGENT) < 64) {
                    __builtin_amdgcn_s_sleep(1);
                    if (++spins >= 8192) {      // insurance re-check via RMW
                        spins = 0;
                        if (__hip_atomic_fetch_add(cp, 0, __ATOMIC_RELAXED,
                                __HIP_MEMORY_SCOPE_AGENT) >= 64) break;
                    }
                }
            }
            __syncthreads();          // broadcast: h[t-1] planes visible
            // ---- stage bf16 hi/lo planes of h[t-1] (sc1 loads, R2 pattern) --
            {
                const char* bh = hb_lane + (size_t)((t - 1) & 1) * HB_PARITY;
                const char* bl = bh + HB_PLANE;
                float4 v[16];
                #pragma unroll
                for (int it = 0; it < 8; it++)
                    asm volatile("global_load_dwordx4 %0, %1, off offset:%2 sc0 sc1"
                                 : "=v"(v[it]) : "v"(bh), "i"(it * 256) : "memory");
                #pragma unroll
                for (int it = 0; it < 8; it++)
                    asm volatile("global_load_dwordx4 %0, %1, off offset:%2 sc0 sc1"
                                 : "=v"(v[8 + it]) : "v"(bl), "i"(it * 256) : "memory");
                asm volatile("s_waitcnt vmcnt(0)" ::: "memory");
                #pragma unroll
                for (int it = 0; it < 8; it++)
                    *(float4*)(dh + it * 256) = v[it];
                #pragma unroll
                for (int it = 0; it < 8; it++)
                    *(float4*)(dl + it * 256) = v[8 + it];
            }
            __syncthreads();
            // ---- MFMA over own k-quarter: 8 k-steps x 3 split products -----
            f32x4 acc0 = {0.f, 0.f, 0.f, 0.f};
            f32x4 acc1 = {0.f, 0.f, 0.f, 0.f};
            #pragma unroll
            for (int ks = 0; ks < 8; ks++) {
                bf16x8 ah = *(const bf16x8*)(ah_base + ks * 64);
                bf16x8 al = *(const bf16x8*)(al_base + ks * 64);
                if (ks & 1) {
                    acc1 = __builtin_amdgcn_mfma_f32_16x16x32_bf16(ah, wh[ks], acc1, 0, 0, 0);
                    acc1 = __builtin_amdgcn_mfma_f32_16x16x32_bf16(al, wh[ks], acc1, 0, 0, 0);
                    acc1 = __builtin_amdgcn_mfma_f32_16x16x32_bf16(ah, wl[ks], acc1, 0, 0, 0);
                } else {
                    acc0 = __builtin_amdgcn_mfma_f32_16x16x32_bf16(ah, wh[ks], acc0, 0, 0, 0);
                    acc0 = __builtin_amdgcn_mfma_f32_16x16x32_bf16(al, wh[ks], acc0, 0, 0, 0);
                    acc0 = __builtin_amdgcn_mfma_f32_16x16x32_bf16(ah, wl[ks], acc0, 0, 0, 0);
                }
            }
            // ---- cross-wave k reduction ------------------------------------
            #pragma unroll
            for (int r = 0; r < 4; r++)
                redp[w * 256 + (kq * 4 + r) * 16 + row] = acc0[r] + acc1[r];
            __syncthreads();
            sum = redp[tid] + redp[256 + tid] + redp[512 + tid] + redp[768 + tid];
        }
        float pre = sum + xw;
        float hn = a_reg * hp + om * tanhf(pre);
        *xwp = hn;                    // plain store: output only, block-local
        if (t == SEQ - 1)
            out[(size_t)BATCH * SEQ * HID + (size_t)bglob * HID + jglob] = hn;
        // producer-side split of OWN value; sc1 stores into next parity planes
        {
            unsigned short hi16, lo16;
            splitf(hn, &hi16, &lo16);
            unsigned hv = hi16, lv = lo16;
            char* ph = ph_base + (size_t)(t & 1) * HB_PARITY;
            char* pl = ph + HB_PLANE;
            asm volatile("global_store_short %0, %1, off sc0 sc1"
                         :: "v"(ph), "v"(hv) : "memory");
            asm volatile("global_store_short %0, %1, off sc0 sc1"
                         :: "v"(pl), "v"(lv) : "memory");
        }
        asm volatile("s_waitcnt vmcnt(0)" ::: "memory");  // drain all stores
        __syncthreads();              // ALL threads' stores drained
        if (tid == 0)
            __hip_atomic_fetch_add(cnt + (size_t)(t * 4 + bs) * CNT_STRIDE, 1,
                    __ATOMIC_RELAXED, __HIP_MEMORY_SCOPE_AGENT);
        hp = hn;
        xwp += HID;
    }
}

extern "C" void kernel_launch(void* const* d_in, const int* in_sizes, int n_in,
                              void* d_out, int out_size, void* d_ws, size_t ws_size,
                              hipStream_t stream) {
    const float* x          = (const float*)d_in[0];
    const float* complexity = (const float*)d_in[1];
    const float* Wrec       = (const float*)d_in[2];
    const float* Win        = (const float*)d_in[3];
    const float* bias       = (const float*)d_in[4];
    const float* tau_bands  = (const float*)d_in[5];
    const float* mixer_w    = (const float*)d_in[6];
    const float* mixer_b    = (const float*)d_in[7];
    float* out = (float*)d_out;

    float* alpha = (float*)d_ws;                               // 256 B
    int*   cnt   = (int*)((char*)d_ws + 256);                  // 262144 B
    unsigned short* hbuf = (unsigned short*)((char*)d_ws + 266240);  // 524288 B

    hipMemsetAsync(cnt, 0, SEQ * 4 * CNT_STRIDE * sizeof(int), stream);
    alpha_kernel<<<1, 64, 0, stream>>>(complexity, tau_bands, mixer_w, mixer_b, alpha);
    in_gemm<<<dim3(32768 / BM, 1024 / BN), 256, 0, stream>>>(x, Win, bias, out);

    hipFuncSetAttribute((const void*)recur_coop,
                        hipFuncAttributeMaxDynamicSharedMemorySize, LDS_TOTAL);
    void* args[] = { (void*)&Wrec, (void*)&alpha, (void*)&out, (void*)&cnt, (void*)&hbuf };
    hipLaunchCooperativeKernel((void*)recur_coop, dim3(256), dim3(256),
                               args, LDS_TOTAL, stream);
}